// Round 1
// baseline (1147.495 us; speedup 1.0000x reference)
//
#include <hip/hip_runtime.h>
#include <hip/hip_fp16.h>

#define T_SEQ 256

typedef _Float16 half8 __attribute__((ext_vector_type(8)));
typedef float float4v __attribute__((ext_vector_type(4)));

__device__ __forceinline__ float fexp2(float x) { return __builtin_amdgcn_exp2f(x); }
__device__ __forceinline__ float frcp(float x) { return __builtin_amdgcn_rcpf(x); }
// sigmoid(x) = 1/(1+2^(-x*log2e))
__device__ __forceinline__ float sigf(float x) { return frcp(1.f + fexp2(-1.4426950408889634f * x)); }
// tanh(x) = 1 - 2/(2^(2x*log2e)+1)
__device__ __forceinline__ float tanhf_(float x) { return 1.f - 2.f * frcp(1.f + fexp2(2.8853900817779268f * x)); }

// ---------------------------------------------------------------------------
// prep: convert w_hh1 [4 chains][512][128] fp32 -> fp16 MFMA-B fragment order
// dst[(((chain*32+tile)*4+kk)*64+lane)*8 + j] = w[g=tile*16+(lane&15)][k=kk*32+(lane>>4)*8+j]
// ---------------------------------------------------------------------------
__global__ __launch_bounds__(256) void prep_whh1(const float* __restrict__ whh1,
                                                 _Float16* __restrict__ dst) {
    int gid = blockIdx.x * 256 + threadIdx.x;  // 0..32767
    int chain = gid >> 13;
    int tile = (gid >> 8) & 31;
    int kk = (gid >> 6) & 3;
    int lane = gid & 63;
    int g = tile * 16 + (lane & 15);
    int k0 = kk * 32 + (lane >> 4) * 8;
    const float* src = &whh1[(chain * 512 + g) * 128 + k0];
    _Float16* d = &dst[(size_t)gid * 8];
#pragma unroll
    for (int j = 0; j < 8; ++j) d[j] = (_Float16)src[j];
}

// ---------------------------------------------------------------------------
// Layer-0 recurrence. Grid: 32 WGs = 4 chains (n*2+d) x 8 batch-groups of 16.
// Block: 512 threads (8 waves). Wave w owns gate tiles {w, w+8, w+16, w+24}
// -> holds i,f,g,o for h-columns [w*16, w*16+16). c-state stays in VGPRs.
// ---------------------------------------------------------------------------
__global__ __launch_bounds__(512, 1) void lstm_l0(
    const float* __restrict__ x, const float* __restrict__ h0,
    const float* __restrict__ c0, const float* __restrict__ wih0,
    const float* __restrict__ whh0, const float* __restrict__ b0,
    _Float16* __restrict__ y0) {
    const int wg = blockIdx.x;
    const int chain = wg >> 3;          // n*2 + d
    const int n = chain >> 1, d = chain & 1;
    const int bbase = (wg & 7) * 16;
    const int tid = threadIdx.x;
    const int wave = tid >> 6, lane = tid & 63;
    const int lrow = lane & 15, lgrp = lane >> 4;

    __shared__ __align__(16) float xs[16][T_SEQ];
    // h in MFMA-A fragment order: hfrag[kk][lane][j] = h[lane&15][kk*32+(lane>>4)*8+j]
    __shared__ __align__(16) _Float16 hfrag[4][64][8];

    // stage this WG's x rows (contiguous in t)
    for (int idx = tid; idx < 16 * T_SEQ; idx += 512) {
        int r = idx >> 8, t = idx & 255;
        xs[r][t] = x[((bbase + r) * 2 + n) * T_SEQ + t];
    }
    // stage initial h (layer 0 state index = n*4 + d)
    const int sidx = n * 4 + d;
    for (int idx = tid; idx < 256; idx += 512) {
        int kk = idx >> 6, l = idx & 63;
        int b = bbase + (l & 15), k0 = kk * 32 + (l >> 4) * 8;
        const float4v* s4 = (const float4v*)&h0[((size_t)(sidx * 128 + b)) * 128 + k0];
        float4v v0 = s4[0], v1 = s4[1];
        _Float16* dstp = &hfrag[kk][l][0];
#pragma unroll
        for (int j = 0; j < 4; ++j) { dstp[j] = (_Float16)v0[j]; dstp[4 + j] = (_Float16)v1[j]; }
    }
    // per-wave weights: w_hh frags in registers (64 VGPR), plus wi/bias scalars
    float wi[4], bi[4];
    half8 wf[4][4];
#pragma unroll
    for (int p = 0; p < 4; ++p) {
        int g = (wave + 8 * p) * 16 + lrow;
        wi[p] = wih0[chain * 512 + g];
        bi[p] = b0[chain * 512 + g];
        const float* srcg = &whh0[(size_t)(chain * 512 + g) * 128];
#pragma unroll
        for (int kk = 0; kk < 4; ++kk) {
            const float4v* s4 = (const float4v*)&srcg[kk * 32 + lgrp * 8];
            float4v v0 = s4[0], v1 = s4[1];
            half8 h;
#pragma unroll
            for (int j = 0; j < 4; ++j) { h[j] = (_Float16)v0[j]; h[4 + j] = (_Float16)v1[j]; }
            wf[p][kk] = h;
        }
    }
    const int hc = wave * 16 + lrow;  // this lane's hidden column
    float creg[4];
#pragma unroll
    for (int jj = 0; jj < 4; ++jj)
        creg[jj] = c0[((size_t)(sidx * 128 + bbase + 4 * lgrp + jj)) * 128 + hc];

    __syncthreads();

    const int kkw = hc >> 5, jd = hc & 7, lsub = (hc >> 3) & 3;

    for (int t = 0; t < T_SEQ; ++t) {
        const int tx = d ? (T_SEQ - 1 - t) : t;
        half8 a[4];
#pragma unroll
        for (int kk = 0; kk < 4; ++kk) a[kk] = *(const half8*)&hfrag[kk][lane][0];
        // acc init = x*w_ih + bias (exact fp32); C/D layout: col=lane&15, row=4*(lane>>4)+jj
        float4v acc[4];
#pragma unroll
        for (int p = 0; p < 4; ++p) {
#pragma unroll
            for (int jj = 0; jj < 4; ++jj)
                acc[p][jj] = fmaf(xs[4 * lgrp + jj][tx], wi[p], bi[p]);
        }
        __syncthreads();  // all waves done reading hfrag before this step's writes
#pragma unroll
        for (int kk = 0; kk < 4; ++kk) {
#pragma unroll
            for (int p = 0; p < 4; ++p)
                acc[p] = __builtin_amdgcn_mfma_f32_16x16x32_f16(a[kk], wf[p][kk], acc[p], 0, 0, 0);
        }
        // gating: acc[0]=i, acc[1]=f, acc[2]=g, acc[3]=o
        float hout[4];
#pragma unroll
        for (int jj = 0; jj < 4; ++jj) {
            float ig = sigf(acc[0][jj]);
            float fg = sigf(acc[1][jj]);
            float gg = tanhf_(acc[2][jj]);
            float og = sigf(acc[3][jj]);
            float c = fmaf(fg, creg[jj], ig * gg);
            creg[jj] = c;
            hout[jj] = og * tanhf_(c);
        }
#pragma unroll
        for (int jj = 0; jj < 4; ++jj) {
            _Float16 hv = (_Float16)hout[jj];
            hfrag[kkw][16 * lsub + 4 * lgrp + jj][jd] = hv;
            // y0[n][b][t][d*128 + hc] (fp16), consumed by layer 1
            y0[(((size_t)(n * 128 + bbase + 4 * lgrp + jj)) * T_SEQ + tx) * 256 + d * 128 + hc] = hv;
        }
        __syncthreads();
    }
}

// ---------------------------------------------------------------------------
// Layer-1 recurrence. Same decomposition. K = 128 (recurrent, streamed from
// prepped L2 copy) + 256 (input y0, w_ih1 held in 128 VGPRs/lane).
// Backward direction only needs its FIRST step (head reads y[:, -1]).
// ---------------------------------------------------------------------------
__global__ __launch_bounds__(512, 1) void lstm_l1(
    const float* __restrict__ h0, const float* __restrict__ c0,
    const float* __restrict__ wih1, const _Float16* __restrict__ whh1f,
    const float* __restrict__ b1, const _Float16* __restrict__ y0,
    float* __restrict__ lo) {
    const int wg = blockIdx.x;
    const int chain = wg >> 3;
    const int n = chain >> 1, d = chain & 1;
    const int bbase = (wg & 7) * 16;
    const int tid = threadIdx.x;
    const int wave = tid >> 6, lane = tid & 63;
    const int lrow = lane & 15, lgrp = lane >> 4;

    __shared__ __align__(16) _Float16 hfrag[4][64][8];

    const int sidx = n * 4 + 2 + d;  // layer 1 state index
    for (int idx = tid; idx < 256; idx += 512) {
        int kk = idx >> 6, l = idx & 63;
        int b = bbase + (l & 15), k0 = kk * 32 + (l >> 4) * 8;
        const float4v* s4 = (const float4v*)&h0[((size_t)(sidx * 128 + b)) * 128 + k0];
        float4v v0 = s4[0], v1 = s4[1];
        _Float16* dstp = &hfrag[kk][l][0];
#pragma unroll
        for (int j = 0; j < 4; ++j) { dstp[j] = (_Float16)v0[j]; dstp[4 + j] = (_Float16)v1[j]; }
    }
    float bi[4];
    half8 wih[4][8];  // 128 VGPR: input-projection weights, loaded once
#pragma unroll
    for (int p = 0; p < 4; ++p) {
        int g = (wave + 8 * p) * 16 + lrow;
        bi[p] = b1[chain * 512 + g];
        const float* srcg = &wih1[(size_t)(chain * 512 + g) * 256];
#pragma unroll
        for (int kk = 0; kk < 8; ++kk) {
            const float4v* s4 = (const float4v*)&srcg[kk * 32 + lgrp * 8];
            float4v v0 = s4[0], v1 = s4[1];
            half8 h;
#pragma unroll
            for (int j = 0; j < 4; ++j) { h[j] = (_Float16)v0[j]; h[4 + j] = (_Float16)v1[j]; }
            wih[p][kk] = h;
        }
    }
    const int hc = wave * 16 + lrow;
    float creg[4];
#pragma unroll
    for (int jj = 0; jj < 4; ++jj)
        creg[jj] = c0[((size_t)(sidx * 128 + bbase + 4 * lgrp + jj)) * 128 + hc];

    __syncthreads();

    const int kkw = hc >> 5, jd = hc & 7, lsub = (hc >> 3) & 3;
    const int nsteps = d ? 1 : T_SEQ;
    const _Float16* whh_base = &whh1f[(size_t)chain * 32 * 4 * 64 * 8];

    for (int t = 0; t < nsteps; ++t) {
        const int tin = d ? (T_SEQ - 1) : t;
        half8 a[4];
#pragma unroll
        for (int kk = 0; kk < 4; ++kk) a[kk] = *(const half8*)&hfrag[kk][lane][0];
        half8 yf[8];
        {
            const _Float16* yb = &y0[(((size_t)(n * 128 + bbase + lrow)) * T_SEQ + tin) * 256 + lgrp * 8];
#pragma unroll
            for (int kk = 0; kk < 8; ++kk) yf[kk] = *(const half8*)&yb[kk * 32];
        }
        float4v acc[4];
#pragma unroll
        for (int p = 0; p < 4; ++p) acc[p] = (float4v){bi[p], bi[p], bi[p], bi[p]};
        __syncthreads();
        // input projection (weights in regs, issued first so whh L2 loads can stream in)
#pragma unroll
        for (int kk = 0; kk < 8; ++kk) {
#pragma unroll
            for (int p = 0; p < 4; ++p)
                acc[p] = __builtin_amdgcn_mfma_f32_16x16x32_f16(yf[kk], wih[p][kk], acc[p], 0, 0, 0);
        }
        // recurrent part (whh frags streamed from L2-resident prepped copy)
#pragma unroll
        for (int kk = 0; kk < 4; ++kk) {
#pragma unroll
            for (int p = 0; p < 4; ++p) {
                int tile = wave + 8 * p;
                half8 wfr = *(const half8*)&whh_base[(size_t)((tile * 4 + kk) * 64 + lane) * 8];
                acc[p] = __builtin_amdgcn_mfma_f32_16x16x32_f16(a[kk], wfr, acc[p], 0, 0, 0);
            }
        }
        float hout[4];
#pragma unroll
        for (int jj = 0; jj < 4; ++jj) {
            float ig = sigf(acc[0][jj]);
            float fg = sigf(acc[1][jj]);
            float gg = tanhf_(acc[2][jj]);
            float og = sigf(acc[3][jj]);
            float c = fmaf(fg, creg[jj], ig * gg);
            creg[jj] = c;
            hout[jj] = og * tanhf_(c);
        }
#pragma unroll
        for (int jj = 0; jj < 4; ++jj)
            hfrag[kkw][16 * lsub + 4 * lgrp + jj][jd] = (_Float16)hout[jj];
        if (t == nsteps - 1) {
            // final output h -> lstm_out[b][n*256 + d*128 + hc]
#pragma unroll
            for (int jj = 0; jj < 4; ++jj)
                lo[(size_t)(bbase + 4 * lgrp + jj) * 512 + n * 256 + d * 128 + hc] = hout[jj];
        }
        __syncthreads();
    }
}

// ---------------------------------------------------------------------------
// FC head: per batch row: fc0(512->256) -> relu(t+LN(t)) -> fc1(256->256)
// -> relu(t+LN(t)) -> fc2(256->64). One WG per row, 256 threads.
// ---------------------------------------------------------------------------
__global__ __launch_bounds__(256) void head_k(
    const float* __restrict__ lo,
    const float* __restrict__ w0, const float* __restrict__ bb0,
    const float* __restrict__ a0, const float* __restrict__ g0,
    const float* __restrict__ w1, const float* __restrict__ bb1,
    const float* __restrict__ a1, const float* __restrict__ g1,
    const float* __restrict__ w2, const float* __restrict__ bb2,
    float* __restrict__ out) {
    const int b = blockIdx.x, j = threadIdx.x;
    const int lane = j & 63, wid = j >> 6;
    __shared__ float row[512];
    __shared__ float buf[256];
    __shared__ float redA[4], redB[4];

    row[j] = lo[b * 512 + j];
    row[256 + j] = lo[b * 512 + 256 + j];
    __syncthreads();

    // fc0
    float s = bb0[j];
#pragma unroll 8
    for (int k = 0; k < 512; ++k) s = fmaf(row[k], w0[k * 256 + j], s);
    // LN0 (unbiased std, +eps on std)
    float v = s, v2 = s * s;
#pragma unroll
    for (int off = 32; off; off >>= 1) { v += __shfl_xor(v, off); v2 += __shfl_xor(v2, off); }
    if (lane == 0) { redA[wid] = v; redB[wid] = v2; }
    __syncthreads();
    float S = redA[0] + redA[1] + redA[2] + redA[3];
    float SS = redB[0] + redB[1] + redB[2] + redB[3];
    float mu = S * (1.f / 256.f);
    float var = (SS - S * mu) * (1.f / 255.f);
    float stdv = sqrtf(var) + 1e-6f;
    float t0 = fmaxf(s + (s - mu) / stdv * a0[j] + g0[j], 0.f);
    buf[j] = t0;
    __syncthreads();

    // fc1
    float s1 = bb1[j];
#pragma unroll 8
    for (int k = 0; k < 256; ++k) s1 = fmaf(buf[k], w1[k * 256 + j], s1);
    v = s1; v2 = s1 * s1;
#pragma unroll
    for (int off = 32; off; off >>= 1) { v += __shfl_xor(v, off); v2 += __shfl_xor(v2, off); }
    if (lane == 0) { redA[wid] = v; redB[wid] = v2; }
    __syncthreads();
    S = redA[0] + redA[1] + redA[2] + redA[3];
    SS = redB[0] + redB[1] + redB[2] + redB[3];
    mu = S * (1.f / 256.f);
    var = (SS - S * mu) * (1.f / 255.f);
    stdv = sqrtf(var) + 1e-6f;
    float t1 = fmaxf(s1 + (s1 - mu) / stdv * a1[j] + g1[j], 0.f);
    __syncthreads();
    buf[j] = t1;
    __syncthreads();

    // fc2
    if (j < 64) {
        float s2 = bb2[j];
#pragma unroll 8
        for (int k = 0; k < 256; ++k) s2 = fmaf(buf[k], w2[k * 64 + j], s2);
        out[b * 64 + j] = s2;
    }
}

extern "C" void kernel_launch(void* const* d_in, const int* in_sizes, int n_in,
                              void* d_out, int out_size, void* d_ws, size_t ws_size,
                              hipStream_t stream) {
    const float* x    = (const float*)d_in[0];
    const float* h0   = (const float*)d_in[1];
    const float* c0   = (const float*)d_in[2];
    const float* wih0 = (const float*)d_in[3];
    const float* whh0 = (const float*)d_in[4];
    const float* bb0  = (const float*)d_in[5];
    const float* wih1 = (const float*)d_in[6];
    const float* whh1 = (const float*)d_in[7];
    const float* bb1  = (const float*)d_in[8];
    const float* wfc0 = (const float*)d_in[9];
    const float* bfc0 = (const float*)d_in[10];
    const float* ln0a = (const float*)d_in[11];
    const float* ln0b = (const float*)d_in[12];
    const float* wfc1 = (const float*)d_in[13];
    const float* bfc1 = (const float*)d_in[14];
    const float* ln1a = (const float*)d_in[15];
    const float* ln1b = (const float*)d_in[16];
    const float* wfc2 = (const float*)d_in[17];
    const float* bfc2 = (const float*)d_in[18];

    // workspace layout:
    //   y0     : fp16 [2][128][256][256] = 32 MiB  (layer-0 output sequence)
    //   whh1f  : fp16 frag-order copy of w_hh1     = 512 KiB
    //   lo     : fp32 [128][512]                   = 256 KiB  (LSTM final outputs)
    char* ws = (char*)d_ws;
    _Float16* y0    = (_Float16*)ws;
    _Float16* whh1f = (_Float16*)(ws + (size_t)33554432);
    float*    lo    = (float*)(ws + (size_t)33554432 + 524288);

    prep_whh1<<<dim3(128), dim3(256), 0, stream>>>(whh1, whh1f);
    lstm_l0<<<dim3(32), dim3(512), 0, stream>>>(x, h0, c0, wih0, whh0, bb0, y0);
    lstm_l1<<<dim3(32), dim3(512), 0, stream>>>(h0, c0, wih1, whh1f, bb1, y0, lo);
    head_k<<<dim3(128), dim3(256), 0, stream>>>(lo, wfc0, bfc0, ln0a, ln0b,
                                                wfc1, bfc1, ln1a, ln1b, wfc2, bfc2,
                                                (float*)d_out);
}

// Round 2
// 750.746 us; speedup vs baseline: 1.5285x; 1.5285x over previous
//
#include <hip/hip_runtime.h>
#include <hip/hip_fp16.h>

#define T_SEQ 256

typedef _Float16 half8 __attribute__((ext_vector_type(8)));
typedef float float4v __attribute__((ext_vector_type(4)));

__device__ __forceinline__ float fexp2(float x) { return __builtin_amdgcn_exp2f(x); }
__device__ __forceinline__ float frcp(float x) { return __builtin_amdgcn_rcpf(x); }
__device__ __forceinline__ float sigf(float x) { return frcp(1.f + fexp2(-1.4426950408889634f * x)); }
__device__ __forceinline__ float tanhf_(float x) { return 1.f - 2.f * frcp(1.f + fexp2(2.8853900817779268f * x)); }

// Barrier that does NOT drain vmcnt: in-flight global stores/prefetches survive.
// LDS correctness: lgkmcnt(0) + s_barrier; memory clobber + sched_barrier(0)
// pin ordering (guide rule #18).
__device__ __forceinline__ void relaxed_barrier() {
    __builtin_amdgcn_sched_barrier(0);
    asm volatile("s_waitcnt lgkmcnt(0)" ::: "memory");
    __builtin_amdgcn_s_barrier();
    asm volatile("" ::: "memory");
    __builtin_amdgcn_sched_barrier(0);
}

// ---------------------------------------------------------------------------
// Layer-0. Grid: 32 WGs = 4 chains (n*2+d) x 8 batch-groups of 16 rows.
// 512 threads (8 waves). Wave w owns gate tiles {w,w+8,w+16,w+24} -> i,f,g,o
// for h-columns [16w,16w+16). c stays in VGPRs. One relaxed barrier/step.
// y0 is written in MFMA-A fragment order:
//   y0f[n][t][bg][kk(8)][lane(64)][j(8)] fp16, frag: y[row=lane&15][c=kk*32+(lane>>4)*8+j]
// ---------------------------------------------------------------------------
__global__ __launch_bounds__(512, 1) void lstm_l0(
    const float* __restrict__ x, const float* __restrict__ h0,
    const float* __restrict__ c0, const float* __restrict__ wih0,
    const float* __restrict__ whh0, const float* __restrict__ b0,
    _Float16* __restrict__ y0f) {
    const int wg = blockIdx.x;
    const int chain = wg >> 3, n = chain >> 1, d = chain & 1;
    const int bg = wg & 7, bbase = bg * 16;
    const int tid = threadIdx.x;
    const int wave = tid >> 6, lane = tid & 63, lrow = lane & 15, lgrp = lane >> 4;

    __shared__ __align__(16) float xsT[T_SEQ][16];          // x transposed: [t][row]
    __shared__ __align__(16) _Float16 hfrag[2][4][64][8];   // double-buffered

    // stage x transposed (once)
    {
        int r = tid >> 5, ck = tid & 31;
        const float* xr = &x[((bbase + r) * 2 + n) * T_SEQ + ck * 8];
        float4v v0 = *(const float4v*)xr, v1 = *(const float4v*)(xr + 4);
#pragma unroll
        for (int i = 0; i < 4; ++i) { xsT[ck * 8 + i][r] = v0[i]; xsT[ck * 8 + 4 + i][r] = v1[i]; }
    }
    const int sidx = n * 4 + d;
    for (int idx = tid; idx < 256; idx += 512) {
        int kk = idx >> 6, l = idx & 63;
        int b = bbase + (l & 15), k0 = kk * 32 + (l >> 4) * 8;
        const float4v* s4 = (const float4v*)&h0[((size_t)(sidx * 128 + b)) * 128 + k0];
        float4v v0 = s4[0], v1 = s4[1];
        _Float16* dp = &hfrag[0][kk][l][0];
#pragma unroll
        for (int j = 0; j < 4; ++j) { dp[j] = (_Float16)v0[j]; dp[4 + j] = (_Float16)v1[j]; }
    }
    float wi[4], bi[4];
    half8 wf[4][4];
#pragma unroll
    for (int p = 0; p < 4; ++p) {
        int g = (wave + 8 * p) * 16 + lrow;
        wi[p] = wih0[chain * 512 + g];
        bi[p] = b0[chain * 512 + g];
        const float* sg = &whh0[(size_t)(chain * 512 + g) * 128];
#pragma unroll
        for (int kk = 0; kk < 4; ++kk) {
            const float4v* s4 = (const float4v*)&sg[kk * 32 + lgrp * 8];
            float4v v0 = s4[0], v1 = s4[1];
            half8 h;
#pragma unroll
            for (int j = 0; j < 4; ++j) { h[j] = (_Float16)v0[j]; h[4 + j] = (_Float16)v1[j]; }
            wf[p][kk] = h;
        }
    }
    const int hc = wave * 16 + lrow;
    float creg[4];
#pragma unroll
    for (int jj = 0; jj < 4; ++jj)
        creg[jj] = c0[((size_t)(sidx * 128 + bbase + 4 * lgrp + jj)) * 128 + hc];
    __syncthreads();

    // y0f store-address constants for this lane
    const int kkst = d * 4 + (wave >> 1);
    const int lanehi = 16 * ((wave & 1) * 2 + (lrow >> 3));
    const int jst = lrow & 7;
    const int kkw = hc >> 5, lsub = (hc >> 3) & 3, jd = hc & 7;

    for (int t = 0; t < T_SEQ; ++t) {
        const int cur = t & 1, nxt = cur ^ 1;
        const int tx = d ? (T_SEQ - 1 - t) : t;
        half8 a[4];
#pragma unroll
        for (int kk = 0; kk < 4; ++kk) a[kk] = *(const half8*)&hfrag[cur][kk][lane][0];
        float4v xv = *(const float4v*)&xsT[tx][4 * lgrp];
        float4v acc[4];
#pragma unroll
        for (int p = 0; p < 4; ++p) {
#pragma unroll
            for (int jj = 0; jj < 4; ++jj) acc[p][jj] = fmaf(xv[jj], wi[p], bi[p]);
        }
#pragma unroll
        for (int kk = 0; kk < 4; ++kk)
#pragma unroll
            for (int p = 0; p < 4; ++p)
                acc[p] = __builtin_amdgcn_mfma_f32_16x16x32_f16(a[kk], wf[p][kk], acc[p], 0, 0, 0);

        _Float16* yb = &y0f[((((size_t)n * 256 + tx) * 8 + bg) * 8 + kkst) * 512 + (size_t)lanehi * 8 + jst];
#pragma unroll
        for (int jj = 0; jj < 4; ++jj) {
            float ig = sigf(acc[0][jj]), fg = sigf(acc[1][jj]);
            float gg = tanhf_(acc[2][jj]), og = sigf(acc[3][jj]);
            float c = fmaf(fg, creg[jj], ig * gg);
            creg[jj] = c;
            float ho = og * tanhf_(c);
            _Float16 hv = (_Float16)ho;
            hfrag[nxt][kkw][16 * lsub + 4 * lgrp + jj][jd] = hv;
            yb[(4 * lgrp + jj) * 8] = hv;   // global store, never drained in-loop
        }
        relaxed_barrier();
    }
}

// ---------------------------------------------------------------------------
// Layer-1. Same decomposition. All weights in VGPRs (wih 128 + whh 64).
// y slice (8KB, contiguous in y0f) prefetched global->reg one step ahead,
// reg->LDS double-buffered. Backward dir needs only its first step (t=255).
// ---------------------------------------------------------------------------
__global__ __launch_bounds__(512, 1) void lstm_l1(
    const float* __restrict__ h0, const float* __restrict__ c0,
    const float* __restrict__ wih1, const float* __restrict__ whh1,
    const float* __restrict__ b1, const _Float16* __restrict__ y0f,
    float* __restrict__ lo) {
    const int wg = blockIdx.x;
    const int chain = wg >> 3, n = chain >> 1, d = chain & 1;
    const int bg = wg & 7, bbase = bg * 16;
    const int tid = threadIdx.x;
    const int wave = tid >> 6, lane = tid & 63, lrow = lane & 15, lgrp = lane >> 4;

    __shared__ __align__(16) _Float16 yfrag[2][8][64][8];   // y in A-frag order, dbuf
    __shared__ __align__(16) _Float16 hfrag[2][4][64][8];

    const int sidx = n * 4 + 2 + d;
    for (int idx = tid; idx < 256; idx += 512) {
        int kk = idx >> 6, l = idx & 63;
        int b = bbase + (l & 15), k0 = kk * 32 + (l >> 4) * 8;
        const float4v* s4 = (const float4v*)&h0[((size_t)(sidx * 128 + b)) * 128 + k0];
        float4v v0 = s4[0], v1 = s4[1];
        _Float16* dp = &hfrag[0][kk][l][0];
#pragma unroll
        for (int j = 0; j < 4; ++j) { dp[j] = (_Float16)v0[j]; dp[4 + j] = (_Float16)v1[j]; }
    }
    float bi[4];
    half8 wih[4][8];   // 128 VGPR
    half8 wf[4][4];    // 64 VGPR
#pragma unroll
    for (int p = 0; p < 4; ++p) {
        int g = (wave + 8 * p) * 16 + lrow;
        bi[p] = b1[chain * 512 + g];
        const float* sg = &wih1[(size_t)(chain * 512 + g) * 256];
#pragma unroll
        for (int kk = 0; kk < 8; ++kk) {
            const float4v* s4 = (const float4v*)&sg[kk * 32 + lgrp * 8];
            float4v v0 = s4[0], v1 = s4[1];
            half8 h;
#pragma unroll
            for (int j = 0; j < 4; ++j) { h[j] = (_Float16)v0[j]; h[4 + j] = (_Float16)v1[j]; }
            wih[p][kk] = h;
        }
        const float* sh = &whh1[(size_t)(chain * 512 + g) * 128];
#pragma unroll
        for (int kk = 0; kk < 4; ++kk) {
            const float4v* s4 = (const float4v*)&sh[kk * 32 + lgrp * 8];
            float4v v0 = s4[0], v1 = s4[1];
            half8 h;
#pragma unroll
            for (int j = 0; j < 4; ++j) { h[j] = (_Float16)v0[j]; h[4 + j] = (_Float16)v1[j]; }
            wf[p][kk] = h;
        }
    }
    const int hc = wave * 16 + lrow;
    float creg[4];
#pragma unroll
    for (int jj = 0; jj < 4; ++jj)
        creg[jj] = c0[((size_t)(sidx * 128 + bbase + 4 * lgrp + jj)) * 128 + hc];

    const int nsteps = d ? 1 : T_SEQ;
    const int t0 = d ? (T_SEQ - 1) : 0;
    // stage y(t0) slice: fully coalesced 8KB contiguous block
    {
        const half8* src = (const half8*)&y0f[(((size_t)n * 256 + t0) * 8 + bg) * 4096];
        ((half8*)&yfrag[0][0][0][0])[tid] = src[tid];
    }
    __syncthreads();

    const int kkw = hc >> 5, lsub = (hc >> 3) & 3, jd = hc & 7;

    for (int t = 0; t < nsteps; ++t) {
        const int cur = t & 1, nxt = cur ^ 1;
        const bool pf = (t + 1 < nsteps);
        half8 yreg;
        if (pf) {  // prefetch next y slice (latency hidden under MFMA+gating)
            const half8* src = (const half8*)&y0f[(((size_t)n * 256 + (t + 1)) * 8 + bg) * 4096];
            yreg = src[tid];
        }
        float4v acc[4];
#pragma unroll
        for (int p = 0; p < 4; ++p) acc[p] = (float4v){bi[p], bi[p], bi[p], bi[p]};
        // unified K=384 MFMA loop, A-frags hand-pipelined 1-deep from LDS
        half8 fcur = *(const half8*)&yfrag[cur][0][lane][0];
#pragma unroll
        for (int kk = 0; kk < 12; ++kk) {
            half8 fnxt;
            if (kk < 7)       fnxt = *(const half8*)&yfrag[cur][kk + 1][lane][0];
            else if (kk < 11) fnxt = *(const half8*)&hfrag[cur][kk - 7][lane][0];
#pragma unroll
            for (int p = 0; p < 4; ++p) {
                half8 B = (kk < 8) ? wih[p][kk] : wf[p][kk - 8];
                acc[p] = __builtin_amdgcn_mfma_f32_16x16x32_f16(fcur, B, acc[p], 0, 0, 0);
            }
            if (kk < 11) fcur = fnxt;
        }
        float hout[4];
#pragma unroll
        for (int jj = 0; jj < 4; ++jj) {
            float ig = sigf(acc[0][jj]), fg = sigf(acc[1][jj]);
            float gg = tanhf_(acc[2][jj]), og = sigf(acc[3][jj]);
            float c = fmaf(fg, creg[jj], ig * gg);
            creg[jj] = c;
            hout[jj] = og * tanhf_(c);
        }
#pragma unroll
        for (int jj = 0; jj < 4; ++jj)
            hfrag[nxt][kkw][16 * lsub + 4 * lgrp + jj][jd] = (_Float16)hout[jj];
        if (pf) ((half8*)&yfrag[nxt][0][0][0])[tid] = yreg;
        if (t == nsteps - 1) {
#pragma unroll
            for (int jj = 0; jj < 4; ++jj)
                lo[(size_t)(bbase + 4 * lgrp + jj) * 512 + n * 256 + d * 128 + hc] = hout[jj];
        }
        relaxed_barrier();
    }
}

// ---------------------------------------------------------------------------
// FC head: fc0(512->256) -> relu(t+LN(t)) -> fc1(256->256) -> relu(t+LN(t))
// -> fc2(256->64). One WG per batch row, 256 threads.
// ---------------------------------------------------------------------------
__global__ __launch_bounds__(256) void head_k(
    const float* __restrict__ lo,
    const float* __restrict__ w0, const float* __restrict__ bb0,
    const float* __restrict__ a0, const float* __restrict__ g0,
    const float* __restrict__ w1, const float* __restrict__ bb1,
    const float* __restrict__ a1, const float* __restrict__ g1,
    const float* __restrict__ w2, const float* __restrict__ bb2,
    float* __restrict__ out) {
    const int b = blockIdx.x, j = threadIdx.x;
    const int lane = j & 63, wid = j >> 6;
    __shared__ float row[512];
    __shared__ float buf[256];
    __shared__ float redA[4], redB[4];

    row[j] = lo[b * 512 + j];
    row[256 + j] = lo[b * 512 + 256 + j];
    __syncthreads();

    float s = bb0[j];
#pragma unroll 8
    for (int k = 0; k < 512; ++k) s = fmaf(row[k], w0[k * 256 + j], s);
    float v = s, v2 = s * s;
#pragma unroll
    for (int off = 32; off; off >>= 1) { v += __shfl_xor(v, off); v2 += __shfl_xor(v2, off); }
    if (lane == 0) { redA[wid] = v; redB[wid] = v2; }
    __syncthreads();
    float S = redA[0] + redA[1] + redA[2] + redA[3];
    float SS = redB[0] + redB[1] + redB[2] + redB[3];
    float mu = S * (1.f / 256.f);
    float var = (SS - S * mu) * (1.f / 255.f);
    float stdv = sqrtf(var) + 1e-6f;
    float t0 = fmaxf(s + (s - mu) / stdv * a0[j] + g0[j], 0.f);
    buf[j] = t0;
    __syncthreads();

    float s1 = bb1[j];
#pragma unroll 8
    for (int k = 0; k < 256; ++k) s1 = fmaf(buf[k], w1[k * 256 + j], s1);
    v = s1; v2 = s1 * s1;
#pragma unroll
    for (int off = 32; off; off >>= 1) { v += __shfl_xor(v, off); v2 += __shfl_xor(v2, off); }
    if (lane == 0) { redA[wid] = v; redB[wid] = v2; }
    __syncthreads();
    S = redA[0] + redA[1] + redA[2] + redA[3];
    SS = redB[0] + redB[1] + redB[2] + redB[3];
    mu = S * (1.f / 256.f);
    var = (SS - S * mu) * (1.f / 255.f);
    stdv = sqrtf(var) + 1e-6f;
    float t1 = fmaxf(s1 + (s1 - mu) / stdv * a1[j] + g1[j], 0.f);
    __syncthreads();
    buf[j] = t1;
    __syncthreads();

    if (j < 64) {
        float s2 = bb2[j];
#pragma unroll 8
        for (int k = 0; k < 256; ++k) s2 = fmaf(buf[k], w2[k * 64 + j], s2);
        out[b * 64 + j] = s2;
    }
}

extern "C" void kernel_launch(void* const* d_in, const int* in_sizes, int n_in,
                              void* d_out, int out_size, void* d_ws, size_t ws_size,
                              hipStream_t stream) {
    const float* x    = (const float*)d_in[0];
    const float* h0   = (const float*)d_in[1];
    const float* c0   = (const float*)d_in[2];
    const float* wih0 = (const float*)d_in[3];
    const float* whh0 = (const float*)d_in[4];
    const float* bb0  = (const float*)d_in[5];
    const float* wih1 = (const float*)d_in[6];
    const float* whh1 = (const float*)d_in[7];
    const float* bb1  = (const float*)d_in[8];
    const float* wfc0 = (const float*)d_in[9];
    const float* bfc0 = (const float*)d_in[10];
    const float* ln0a = (const float*)d_in[11];
    const float* ln0b = (const float*)d_in[12];
    const float* wfc1 = (const float*)d_in[13];
    const float* bfc1 = (const float*)d_in[14];
    const float* ln1a = (const float*)d_in[15];
    const float* ln1b = (const float*)d_in[16];
    const float* wfc2 = (const float*)d_in[17];
    const float* bfc2 = (const float*)d_in[18];

    // workspace: y0f fp16 [2][256][8][8][64][8] = 32 MiB; lo fp32 [128][512] = 256 KiB
    char* ws = (char*)d_ws;
    _Float16* y0f = (_Float16*)ws;
    float*    lo  = (float*)(ws + (size_t)33554432);

    lstm_l0<<<dim3(32), dim3(512), 0, stream>>>(x, h0, c0, wih0, whh0, bb0, y0f);
    lstm_l1<<<dim3(32), dim3(512), 0, stream>>>(h0, c0, wih1, whh1, bb1, y0f, lo);
    head_k<<<dim3(128), dim3(256), 0, stream>>>(lo, wfc0, bfc0, ln0a, ln0b,
                                                wfc1, bfc1, ln1a, ln1b, wfc2, bfc2,
                                                (float*)d_out);
}